// Round 10
// baseline (313.028 us; speedup 1.0000x reference)
//
#include <hip/hip_runtime.h>
#include <hip/hip_bf16.h>

// Problem constants
#define NN 384
#define CUTOFF2 144.0f
#define GAMMA 1.7777778f   // (16/12)^2

// packed B-frag layout per layer (u32 units): [W1b 8192 | We 2048 | W2 8192 | C1 8192]
#define PK_L 26624
#define PK_WE 8192
#define PK_W2 10240
#define PK_C1 18432

#define STG_F32 1152                              // 32 rows x 36 f32 per-wave stage
#define MAIN_SMEM ((PK_L + 9216 + 512)*4)         // 145408 B -> 1 block/CU

// ws byte offsets
#define O_X1 0
#define O_X2 4608
#define O_A 9216
#define O_AGG 205824
#define O_HBF 402432
#define O_EREC 500736      // 384*384*16
#define O_UNITS 2860032
#define O_SYNC 2878464     // 32 B: ucnt[3] + bars[5]

#define AGENT __HIP_MEMORY_SCOPE_AGENT
#define RLX __ATOMIC_RELAXED

typedef __bf16 bf16x8 __attribute__((ext_vector_type(8)));
typedef float f32x4 __attribute__((ext_vector_type(4)));
typedef unsigned long long u64;

template<typename T>
__device__ __forceinline__ T cload(const T* p){ return __hip_atomic_load((T*)p, RLX, AGENT); }
template<typename T>
__device__ __forceinline__ void cstore(T* p, T v){ __hip_atomic_store(p, v, RLX, AGENT); }
__device__ __forceinline__ float cadd(float* p, float v){
  return __hip_atomic_fetch_add(p, v, RLX, AGENT);
}
__device__ __forceinline__ int caddi(int* p, int v){
  return __hip_atomic_fetch_add(p, v, RLX, AGENT);
}

union ER { struct { float dx, dy, dz; unsigned j; } e; u64 u[2]; };

__device__ __forceinline__ unsigned short f2bf(float f){
  unsigned u = __float_as_uint(f);
  return (unsigned short)((u + 0x7fffu + ((u >> 16) & 1u)) >> 16);  // RNE
}
__device__ __forceinline__ unsigned pk2(float a, float b){
  return ((unsigned)f2bf(b) << 16) | f2bf(a);
}
__device__ __forceinline__ float silu(float x){ return x / (1.0f + __expf(-x)); }

// ---- fence-free grid barrier (256 blocks co-resident @ 1 block/CU; all shared
// data moves via agent-scope accesses -> no L2 writeback needed). Verified R6.
__device__ __forceinline__ void gridbar(int* bar){
  asm volatile("s_waitcnt vmcnt(0) lgkmcnt(0)" ::: "memory");
  __syncthreads();
  if (threadIdx.x == 0) {
    caddi(bar, 1);
    while (__hip_atomic_load(bar, RLX, AGENT) < 256)
      __builtin_amdgcn_s_sleep(2);
  }
  __syncthreads();
  asm volatile("" ::: "memory");
}

// ---- per-block weight pack: layer weights (read-only inputs, cached) -> own LDS
__device__ __forceinline__ void pack_lds(int tid, const float* __restrict__ eW1l,
                                         const float* __restrict__ eW2l,
                                         const float* __restrict__ cW1l,
                                         unsigned* __restrict__ pkdst){
  for (int r = tid; r < PK_L; r += 512) {
    const float* src; int fr; int isWe = 0;
    if (r < PK_WE)      { fr = r;         src = eW1l + 128*128; }
    else if (r < PK_W2) { fr = r - PK_WE; src = eW1l + 256*128; isWe = 1; }
    else if (r < PK_C1) { fr = r - PK_W2; src = eW2l; }
    else                { fr = r - PK_C1; src = cW1l; }
    int tp = fr & 3, l = (fr >> 2) & 63, nc = fr >> 8;
    int n, k;
    if (!isWe) { n = nc >> 2; int c = nc & 3; k = c*32 + ((l>>4)<<3) + 2*tp; }
    else       { n = nc;                      k = ((l>>4)<<3) + 2*tp; }
    int nn = n*16 + (l & 15);
    float w0, w1;
    if (isWe) { w0 = (k < 16)   ? src[k*128+nn]     : 0.f;
                w1 = (k+1 < 16) ? src[(k+1)*128+nn] : 0.f; }
    else      { w0 = src[k*128+nn]; w1 = src[(k+1)*128+nn]; }
    pkdst[r] = ((unsigned)f2bf(w1) << 16) | f2bf(w0);
  }
}

// ---- scan: row's radius graph -> 16B records {diff,j} (agent), self-publish units
__device__ __forceinline__ void scan_f(
    int row, int rsel, int o, bool v, const float* __restrict__ x, bool xa,
    u64* __restrict__ erec8, int* __restrict__ units, int* __restrict__ ucntSlot,
    int* scn){
  int* scnt = scn + rsel*2; int* sbase = scnt + 1;
  if (v && o == 0) *scnt = 0;
  __syncthreads();
  if (v) {
    float xi0, xi1, xi2;
    if (xa) { xi0=cload(x+row*3); xi1=cload(x+row*3+1); xi2=cload(x+row*3+2); }
    else    { xi0=x[row*3];       xi1=x[row*3+1];       xi2=x[row*3+2]; }
    for (int j = o; j < 384; j += 128) {
      float q0,q1,q2;
      if (xa) { q0=cload(x+j*3); q1=cload(x+j*3+1); q2=cload(x+j*3+2); }
      else    { q0=x[j*3];       q1=x[j*3+1];       q2=x[j*3+2]; }
      float d0=xi0-q0, d1=xi1-q1, d2=xi2-q2;
      float dd = d0*d0 + d1*d1 + d2*d2;
      bool msk = ((dd < CUTOFF2) && (j != row)) || (j == row-1) || (j == row+1);
      if (msk) {
        int ss = atomicAdd(scnt, 1);
        ER er; er.e.dx=d0; er.e.dy=d1; er.e.dz=d2; er.e.j=(unsigned)j;
        u64* rp = erec8 + (unsigned)(row*384 + ss)*2;
        cstore(rp, er.u[0]); cstore(rp+1, er.u[1]);
      }
    }
  }
  __syncthreads();
  if (v) {
    int cnt = *scnt;
    int p = (32 - (cnt & 31)) & 31;
    if (o < p) {
      ER er; er.e.dx=0.f; er.e.dy=0.f; er.e.dz=0.f; er.e.j=(unsigned)row;
      u64* rp = erec8 + (unsigned)(row*384 + cnt + o)*2;
      cstore(rp, er.u[0]); cstore(rp+1, er.u[1]);
    }
    if (o == 0) *sbase = caddi(ucntSlot, (cnt + 31) >> 5);
  }
  __syncthreads();
  if (v) {
    int cnt = *scnt, nu = (cnt + 31) >> 5;
    if (o < nu) {
      int nv = cnt - (o << 5); if (nv > 32) nv = 32;
      cstore(units + *sbase + o, row | (o << 9) | (nv << 13));
    }
  }
}

// ---- C-layout -> A-frag transpose via per-wave f32 LDS pad (wave-private)
#define TRANSFORM(VA, VB, FA, FB)                                              \
  _Pragma("unroll")                                                            \
  for (int c = 0; c < 4; ++c) {                                                \
    _Pragma("unroll")                                                          \
    for (int tl = 0; tl < 2; ++tl) {                                           \
      int t = 2*c + tl;                                                        \
      _Pragma("unroll")                                                        \
      for (int r = 0; r < 4; ++r) {                                            \
        stg[(quad*4 + r)*36 + tl*16 + col0] = VA[t][r];                        \
        stg[(16 + quad*4 + r)*36 + tl*16 + col0] = VB[t][r];                   \
      }                                                                        \
    }                                                                          \
    float4 lo = *(const float4*)(stg + col0*36 + quad*8);                      \
    float4 hi = *(const float4*)(stg + col0*36 + quad*8 + 4);                  \
    FA[c].u = make_uint4(pk2(lo.x,lo.y), pk2(lo.z,lo.w),                       \
                         pk2(hi.x,hi.y), pk2(hi.z,hi.w));                      \
    float4 lo2 = *(const float4*)(stg + (16 + col0)*36 + quad*8);              \
    float4 hi2 = *(const float4*)(stg + (16 + col0)*36 + quad*8 + 4);          \
    FB[c].u = make_uint4(pk2(lo2.x,lo2.y), pk2(lo2.z,lo2.w),                   \
                         pk2(hi2.x,hi2.y), pk2(hi2.z,hi2.w));                  \
  }

// ---- MFMA edge phase: wave = one unit (32 same-receiver edges), block-first spread
__device__ void edge_f(unsigned* __restrict__ smem, float* __restrict__ stage,
    float* __restrict__ x_out, const float* __restrict__ Ag,
    const unsigned short* __restrict__ hbf, const u64* __restrict__ erec8,
    const int* __restrict__ units, int* __restrict__ ucntSlot,
    float* __restrict__ agg, const float* __restrict__ eb2g,
    const float* __restrict__ cb1g, const float* __restrict__ cw2g){
  const int tid = threadIdx.x, q = tid & 63, s = tid >> 6;
  const int U = cload(ucntSlot);
  const int col0 = q & 15, quad = q >> 4;
  float* stg = stage + s*STG_F32;
  const f32x4 z4 = {0.f, 0.f, 0.f, 0.f};
  union U8 { uint4 u; u64 w[2]; bf16x8 v; };
  const u64* hb = (const u64*)hbf;

  float eb2v[8], cb1v[8], cw2v[8];
  #pragma unroll
  for (int t = 0; t < 8; ++t) {
    int c = t*16 + col0;
    eb2v[t] = eb2g[c]; cb1v[t] = cb1g[c]; cw2v[t] = cw2g[c];
  }

  for (int u = blockIdx.x + 256*s; u < U; u += 2048) {
    const int desc = cload(units + u);
    const int i = desc & 511, b = (desc >> 9) & 15, nvalid = (desc >> 13) & 63;
    float Aval[8];
    #pragma unroll
    for (int t = 0; t < 8; ++t) Aval[t] = cload(Ag + i*128 + t*16 + col0);
    ER e0, e1;
    const u64* r0 = erec8 + (unsigned)(i*384 + b*32 + col0)*2;
    const u64* r1 = erec8 + (unsigned)(i*384 + b*32 + 16 + col0)*2;
    e0.u[0] = cload(r0); e0.u[1] = cload(r0 + 1);
    e1.u[0] = cload(r1); e1.u[1] = cload(r1 + 1);
    const int j0 = (int)e0.e.j, j1 = (int)e1.e.j;
    const float d0x = e0.e.dx, d0y = e0.e.dy, d0z = e0.e.dz;
    const float d1x = e1.e.dx, d1y = e1.e.dy, d1z = e1.e.dz;
    const float dd0 = sqrtf(d0x*d0x + d0y*d0y + d0z*d0z);
    const float dd1 = sqrtf(d1x*d1x + d1y*d1y + d1z*d1z);

    U8 ha0[4], ha1[4];
    #pragma unroll
    for (int c = 0; c < 4; ++c) {
      int off0 = (j0*128 + c*32 + quad*8) >> 2;
      int off1 = (j1*128 + c*32 + quad*8) >> 2;
      ha0[c].w[0] = cload(hb + off0); ha0[c].w[1] = cload(hb + off0 + 1);
      ha1[c].w[0] = cload(hb + off1); ha1[c].w[1] = cload(hb + off1 + 1);
    }

    U8 cve0, cve1;
    if (q < 32) {
      #pragma unroll
      for (int tp = 0; tp < 4; ++tp) {
        float k0 = (float)(quad*8 + 2*tp);
        float t00 = dd0 - 0.8f*k0, t01 = dd0 - 0.8f*(k0+1.f);
        float t10 = dd1 - 0.8f*k0, t11 = dd1 - 0.8f*(k0+1.f);
        (&cve0.u.x)[tp] = pk2(__expf(-GAMMA*t00*t00), __expf(-GAMMA*t01*t01));
        (&cve1.u.x)[tp] = pk2(__expf(-GAMMA*t10*t10), __expf(-GAMMA*t11*t11));
      }
    } else { cve0.u = make_uint4(0,0,0,0); cve1.u = make_uint4(0,0,0,0); }

    // GEMM1: m1 = silu(h_j@W1b + e@We + A_i), 32 rows
    f32x4 acc0[8], acc1[8];
    #pragma unroll
    for (int t = 0; t < 8; ++t) { acc0[t] = z4; acc1[t] = z4; }
    #pragma unroll
    for (int t = 0; t < 8; ++t) {
      #pragma unroll
      for (int c = 0; c < 4; ++c) {
        bf16x8 w = *(const bf16x8*)(smem + ((t*4 + c)*64 + q)*4);
        acc0[t] = __builtin_amdgcn_mfma_f32_16x16x32_bf16(ha0[c].v, w, acc0[t], 0, 0, 0);
        acc1[t] = __builtin_amdgcn_mfma_f32_16x16x32_bf16(ha1[c].v, w, acc1[t], 0, 0, 0);
      }
      bf16x8 we = *(const bf16x8*)(smem + PK_WE + (t*64 + q)*4);
      acc0[t] = __builtin_amdgcn_mfma_f32_16x16x32_bf16(cve0.v, we, acc0[t], 0, 0, 0);
      acc1[t] = __builtin_amdgcn_mfma_f32_16x16x32_bf16(cve1.v, we, acc1[t], 0, 0, 0);
    }
    #pragma unroll
    for (int t = 0; t < 8; ++t)
      #pragma unroll
      for (int r = 0; r < 4; ++r) {
        acc0[t][r] = silu(acc0[t][r] + Aval[t]);
        acc1[t][r] = silu(acc1[t][r] + Aval[t]);
      }

    U8 a20[4], a21[4];
    TRANSFORM(acc0, acc1, a20, a21);

    // GEMM2: m = silu(m1@eW2 + eb2)
    f32x4 m0[8], m1v[8];
    #pragma unroll
    for (int t = 0; t < 8; ++t) { m0[t] = z4; m1v[t] = z4; }
    #pragma unroll
    for (int t = 0; t < 8; ++t)
      #pragma unroll
      for (int c = 0; c < 4; ++c) {
        bf16x8 w = *(const bf16x8*)(smem + PK_W2 + ((t*4 + c)*64 + q)*4);
        m0[t] = __builtin_amdgcn_mfma_f32_16x16x32_bf16(a20[c].v, w, m0[t], 0, 0, 0);
        m1v[t] = __builtin_amdgcn_mfma_f32_16x16x32_bf16(a21[c].v, w, m1v[t], 0, 0, 0);
      }
    #pragma unroll
    for (int t = 0; t < 8; ++t) {
      float cs = 0.f;
      #pragma unroll
      for (int r = 0; r < 4; ++r) {
        m0[t][r] = silu(m0[t][r] + eb2v[t]);
        m1v[t][r] = silu(m1v[t][r] + eb2v[t]);
        if (quad*4 + r < nvalid) cs += m0[t][r];
        if (16 + quad*4 + r < nvalid) cs += m1v[t][r];
      }
      cs += __shfl_xor(cs, 16); cs += __shfl_xor(cs, 32);
      if (q < 16) cadd(&agg[i*128 + t*16 + q], cs);
    }

    U8 a30[4], a31[4];
    TRANSFORM(m0, m1v, a30, a31);

    // GEMM3: c1 = silu(m@cW1 + cb1); w_row = c1 . cW2
    f32x4 c30[8], c31[8];
    #pragma unroll
    for (int t = 0; t < 8; ++t) { c30[t] = z4; c31[t] = z4; }
    #pragma unroll
    for (int t = 0; t < 8; ++t)
      #pragma unroll
      for (int c = 0; c < 4; ++c) {
        bf16x8 w = *(const bf16x8*)(smem + PK_C1 + ((t*4 + c)*64 + q)*4);
        c30[t] = __builtin_amdgcn_mfma_f32_16x16x32_bf16(a30[c].v, w, c30[t], 0, 0, 0);
        c31[t] = __builtin_amdgcn_mfma_f32_16x16x32_bf16(a31[c].v, w, c31[t], 0, 0, 0);
      }
    float p0[4], p1[4];
    #pragma unroll
    for (int r = 0; r < 4; ++r) {
      float pa = 0.f, pb = 0.f;
      #pragma unroll
      for (int t = 0; t < 8; ++t) {
        pa += silu(c30[t][r] + cb1v[t]) * cw2v[t];
        pb += silu(c31[t][r] + cb1v[t]) * cw2v[t];
      }
      if (quad*4 + r >= nvalid) pa = 0.f;
      if (16 + quad*4 + r >= nvalid) pb = 0.f;
      p0[r] = pa; p1[r] = pb;
    }
    #pragma unroll
    for (int r = 0; r < 4; ++r)
      #pragma unroll
      for (int off = 1; off < 16; off <<= 1) {
        p0[r] += __shfl_xor(p0[r], off);
        p1[r] += __shfl_xor(p1[r], off);
      }
    float dx0 = 0.f, dx1 = 0.f, dx2 = 0.f;
    #pragma unroll
    for (int r = 0; r < 4; ++r) {
      int el = quad*4 + r;
      float s0 = __shfl(d0x, el), s1 = __shfl(d0y, el), s2 = __shfl(d0z, el);
      if (col0 == 0) { dx0 += p0[r]*s0; dx1 += p0[r]*s1; dx2 += p0[r]*s2; }
      float u0 = __shfl(d1x, el), u1 = __shfl(d1y, el), u2 = __shfl(d1z, el);
      if (col0 == 0) { dx0 += p1[r]*u0; dx1 += p1[r]*u1; dx2 += p1[r]*u2; }
    }
    dx0 += __shfl_xor(dx0, 16); dx0 += __shfl_xor(dx0, 32);
    dx1 += __shfl_xor(dx1, 16); dx1 += __shfl_xor(dx1, 32);
    dx2 += __shfl_xor(dx2, 16); dx2 += __shfl_xor(dx2, 32);
    if (q == 0) {
      cadd(&x_out[i*3 + 0], dx0);
      cadd(&x_out[i*3 + 1], dx1);
      cadd(&x_out[i*3 + 2], dx2);
    }
  }
}

// ---- node phase (blocks 0..127, 3 rows each): cached weight loads, 4-way split-K
__device__ void node_f(int b, int tid,
    const float* __restrict__ nW1l, const float* __restrict__ nb1l,
    const float* __restrict__ nW2l, const float* __restrict__ nb2l,
    const float* __restrict__ eW1a, const float* __restrict__ eb1a,
    float* __restrict__ hloc, float* __restrict__ stage,
    unsigned short* __restrict__ hbf, float* __restrict__ agg, float* __restrict__ A,
    const float* __restrict__ xsrc, float* __restrict__ xdst,
    const float* __restrict__ anchor, bool subMean,
    u64* __restrict__ erec8, int* __restrict__ units, int* __restrict__ ucntSlot){
  float* scratch = stage;            // 12*128
  float* stl     = stage + 1536;     // 3*128
  float* sgl     = stage + 2048;     // 3*128
  int*   scn     = (int*)(stage + 2944);
  float* ssum    = stage + 2952;
  const int o = tid & 127, q4 = tid >> 7;
  const int row = b*3 + q4;
  const bool v = q4 < 3;

  if (subMean) {
    if (tid < 3) ssum[tid] = 0.f;
    __syncthreads();
    if (tid < 384) {
      atomicAdd(&ssum[0], anchor[tid*3]);
      atomicAdd(&ssum[1], anchor[tid*3+1]);
      atomicAdd(&ssum[2], anchor[tid*3+2]);
    }
    __syncthreads();
  }
  if (v) {
    sgl[q4*128 + o] = cload(agg + row*128 + o);
    cstore(agg + row*128 + o, 0.f);
    if (o < 3) {
      float m = subMean ? ssum[o]*(1.f/384.f) : 0.f;
      cstore(xdst + row*3 + o, cload(xsrc + row*3 + o) - m);
    }
  }
  __syncthreads();
  // matvec1: [h|agg] @ nW1, K=256 split 4 ways
  {
    float p0=0,p1=0,p2=0;
    if (q4 < 2) {
      int k0 = q4*64;
      #pragma unroll 8
      for (int k = k0; k < k0+64; ++k) {
        float wv = nW1l[k*128 + o];
        p0 += hloc[k]*wv; p1 += hloc[128+k]*wv; p2 += hloc[256+k]*wv;
      }
    } else {
      int k0 = (q4-2)*64;
      #pragma unroll 8
      for (int k = k0; k < k0+64; ++k) {
        float wv = nW1l[(128+k)*128 + o];
        p0 += sgl[k]*wv; p1 += sgl[128+k]*wv; p2 += sgl[256+k]*wv;
      }
    }
    scratch[(q4*3+0)*128+o]=p0; scratch[(q4*3+1)*128+o]=p1; scratch[(q4*3+2)*128+o]=p2;
  }
  __syncthreads();
  if (v) {
    float s = nb1l[o];
    #pragma unroll
    for (int q = 0; q < 4; ++q) s += scratch[(q*3+q4)*128+o];
    stl[q4*128 + o] = silu(s);
  }
  __syncthreads();
  // matvec2: st @ nW2, K=128
  {
    float p0=0,p1=0,p2=0;
    int k0 = q4*32;
    #pragma unroll 8
    for (int k = k0; k < k0+32; ++k) {
      float wv = nW2l[k*128 + o];
      p0 += stl[k]*wv; p1 += stl[128+k]*wv; p2 += stl[256+k]*wv;
    }
    scratch[(q4*3+0)*128+o]=p0; scratch[(q4*3+1)*128+o]=p1; scratch[(q4*3+2)*128+o]=p2;
  }
  __syncthreads();
  if (v) {
    float s = nb2l[o] + hloc[q4*128 + o];
    #pragma unroll
    for (int q = 0; q < 4; ++q) s += scratch[(q*3+q4)*128+o];
    hloc[q4*128 + o] = s;
    cstore(hbf + row*128 + o, f2bf(s));
  }
  __syncthreads();
  // matvec3: h_new @ W1a(next), K=128 -> A
  {
    float p0=0,p1=0,p2=0;
    int k0 = q4*32;
    #pragma unroll 8
    for (int k = k0; k < k0+32; ++k) {
      float wv = eW1a[k*128 + o];
      p0 += hloc[k]*wv; p1 += hloc[128+k]*wv; p2 += hloc[256+k]*wv;
    }
    scratch[(q4*3+0)*128+o]=p0; scratch[(q4*3+1)*128+o]=p1; scratch[(q4*3+2)*128+o]=p2;
  }
  __syncthreads();
  if (v) {
    float s = eb1a[o];
    #pragma unroll
    for (int q = 0; q < 4; ++q) s += scratch[(q*3+q4)*128+o];
    cstore(A + row*128 + o, s);
  }
  scan_f(row, q4, o, v, xsrc, true, erec8, units, ucntSlot, scn);
}

// ---- the whole decoder in one kernel; weights packed per-block per-layer
__global__ __launch_bounds__(512, 1) void k_main(
    const float* __restrict__ z, const float* __restrict__ anchor,
    const float* __restrict__ projW, const float* __restrict__ projb,
    const float* __restrict__ eW1, const float* __restrict__ eb1,
    const float* __restrict__ eW2, const float* __restrict__ eb2,
    const float* __restrict__ nW1, const float* __restrict__ nb1,
    const float* __restrict__ nW2, const float* __restrict__ nb2,
    const float* __restrict__ cW1, const float* __restrict__ cb1,
    const float* __restrict__ cW2, float* __restrict__ out,
    float* __restrict__ x1, float* __restrict__ x2,
    float* __restrict__ A, float* __restrict__ agg,
    unsigned short* __restrict__ hbf, u64* __restrict__ erec8,
    int* __restrict__ units, int* __restrict__ sync_){
  extern __shared__ unsigned smem[];
  float* stage = (float*)(smem + PK_L);   // 9216 f32
  float* hloc  = stage + 9216;            // 512 f32 (3x128 used)
  const int tid = threadIdx.x, b = blockIdx.x;
  int* ucnt = sync_;        // [0..2]
  int* bars = sync_ + 3;    // [0..4]

  // ---- P0: pack layer0 weights; blocks<128: proj + seeds + scan0
  pack_lds(tid, eW1, eW2, cW1, smem);
  if (b < 128) {
    float* scratch = stage;
    float* szl = stage + 2048;   // 3*64
    int* scn = (int*)(stage + 2944);
    const int o = tid & 127, q4 = tid >> 7;
    const int row = b*3 + q4;
    const bool v = q4 < 3;
    if (v) {
      if (o < 64) szl[q4*64 + o] = z[row*64 + o];
      cstore(agg + row*128 + o, 0.f);
      if (o < 3) cstore(x1 + row*3 + o, anchor[row*3 + o]);
    }
    __syncthreads();
    {  // proj: K=64 split 4 ways
      float p0=0,p1=0,p2=0;
      int k0 = q4*16;
      #pragma unroll
      for (int k = k0; k < k0+16; ++k) {
        float wv = projW[k*128 + o];
        p0 += szl[k]*wv; p1 += szl[64+k]*wv; p2 += szl[128+k]*wv;
      }
      scratch[(q4*3+0)*128+o]=p0; scratch[(q4*3+1)*128+o]=p1; scratch[(q4*3+2)*128+o]=p2;
    }
    __syncthreads();
    if (v) {
      float hh = projb[o];
      #pragma unroll
      for (int q = 0; q < 4; ++q) hh += scratch[(q*3+q4)*128+o];
      hloc[q4*128 + o] = hh;
      cstore(hbf + row*128 + o, f2bf(hh));
    }
    __syncthreads();
    {  // A = eb1 + h @ W1a(layer0), K=128
      float p0=0,p1=0,p2=0;
      int k0 = q4*32;
      #pragma unroll 8
      for (int k = k0; k < k0+32; ++k) {
        float wv = eW1[k*128 + o];
        p0 += hloc[k]*wv; p1 += hloc[128+k]*wv; p2 += hloc[256+k]*wv;
      }
      scratch[(q4*3+0)*128+o]=p0; scratch[(q4*3+1)*128+o]=p1; scratch[(q4*3+2)*128+o]=p2;
    }
    __syncthreads();
    if (v) {
      float s = eb1[o];
      #pragma unroll
      for (int q = 0; q < 4; ++q) s += scratch[(q*3+q4)*128+o];
      cstore(A + row*128 + o, s);
    }
    scan_f(row, q4, o, v, anchor, false, erec8, units, ucnt + 0, scn);
  }
  gridbar(bars + 0);

  // ---- P1: edge layer0 -> x1
  edge_f(smem, stage, x1, A, hbf, erec8, units, ucnt + 0, agg, eb2, cb1, cW2);
  gridbar(bars + 1);

  // ---- P2: repack layer1; node0 (+A for L1) + scan1(x1); seed x2=x1
  pack_lds(tid, eW1 + 272*128, eW2 + 128*128, cW1 + 128*128, smem);
  if (b < 128)
    node_f(b, tid, nW1, nb1, nW2, nb2, eW1 + 272*128, eb1 + 128,
           hloc, stage, hbf, agg, A, x1, x2, anchor, false,
           erec8, units, ucnt + 1);
  gridbar(bars + 2);

  // ---- P3: edge layer1 -> x2
  edge_f(smem, stage, x2, A, hbf, erec8, units, ucnt + 1, agg,
         eb2 + 128, cb1 + 128, cW2 + 128);
  gridbar(bars + 3);

  // ---- P4: repack layer2; node1 (+A for L2) + scan2(x2); seed out = x2 - mean
  pack_lds(tid, eW1 + 2*272*128, eW2 + 2*128*128, cW1 + 2*128*128, smem);
  if (b < 128)
    node_f(b, tid, nW1 + 256*128, nb1 + 128, nW2 + 128*128, nb2 + 128,
           eW1 + 2*272*128, eb1 + 256,
           hloc, stage, hbf, agg, A, x2, out, anchor, true,
           erec8, units, ucnt + 2);
  gridbar(bars + 4);

  // ---- P5: edge layer2 -> out
  edge_f(smem, stage, out, A, hbf, erec8, units, ucnt + 2, agg,
         eb2 + 256, cb1 + 256, cW2 + 256);
}

extern "C" void kernel_launch(void* const* d_in, const int* in_sizes, int n_in,
                              void* d_out, int out_size, void* d_ws, size_t ws_size,
                              hipStream_t stream){
  const float* z      = (const float*)d_in[0];
  const float* anchor = (const float*)d_in[1];
  const float* projW  = (const float*)d_in[2];
  const float* projb  = (const float*)d_in[3];
  const float* eW1    = (const float*)d_in[4];
  const float* eb1    = (const float*)d_in[5];
  const float* eW2    = (const float*)d_in[6];
  const float* eb2    = (const float*)d_in[7];
  const float* nW1    = (const float*)d_in[8];
  const float* nb1    = (const float*)d_in[9];
  const float* nW2    = (const float*)d_in[10];
  const float* nb2    = (const float*)d_in[11];
  const float* cW1    = (const float*)d_in[12];
  const float* cb1    = (const float*)d_in[13];
  const float* cW2    = (const float*)d_in[14];
  float* out = (float*)d_out;

  char* w = (char*)d_ws;
  float* x1  = (float*)(w + O_X1);
  float* x2  = (float*)(w + O_X2);
  float* A   = (float*)(w + O_A);
  float* agg = (float*)(w + O_AGG);
  unsigned short* hbf = (unsigned short*)(w + O_HBF);
  u64* erec8 = (u64*)(w + O_EREC);
  int* units = (int*)(w + O_UNITS);
  int* sync_ = (int*)(w + O_SYNC);

  hipFuncSetAttribute((const void*)k_main, hipFuncAttributeMaxDynamicSharedMemorySize, MAIN_SMEM);

  hipMemsetAsync(sync_, 0, 32, stream);   // ucnt[3] + bars[5]
  k_main<<<256, 512, MAIN_SMEM, stream>>>(
      z, anchor, projW, projb, eW1, eb1, eW2, eb2, nW1, nb1, nW2, nb2,
      cW1, cb1, cW2, out, x1, x2, A, agg, hbf, erec8, units, sync_);
}

// Round 11
// 189.054 us; speedup vs baseline: 1.6558x; 1.6558x over previous
//
#include <hip/hip_runtime.h>
#include <hip/hip_bf16.h>

// Problem constants
#define NN 384
#define CUTOFF2 144.0f
#define GAMMA 1.7777778f   // (16/12)^2

// packed B-frag layout per layer (u32 units): [W1b 8192 | We 2048 | W2 8192 | C1 8192]
#define PK_L 26624
#define PK_WE 8192
#define PK_W2 10240
#define PK_C1 18432

#define STG_F32 1152                      // 32 rows x 36 f32 per-wave stage
#define EDGE_SMEM ((PK_L + 8*STG_F32)*4)  // 143360 B -> 1 block/CU

// ws byte offsets
#define O_XA 0
#define O_XB 4608
#define O_H 9216
#define O_A 205824
#define O_AGG 402432
#define O_HBF 599040
#define O_EREC 697344      // 384*384*16
#define O_UNITS 3056640
#define O_UCNT 3075072     // 3 ints, zeroed by hipMemsetAsync
#define O_MEAN 3075136     // 3 floats
#define O_PK 3075200

typedef __bf16 bf16x8 __attribute__((ext_vector_type(8)));
typedef float f32x4 __attribute__((ext_vector_type(4)));

union ER { struct { float dx, dy, dz; unsigned j; } e; uint4 u4; };

__device__ __forceinline__ unsigned short f2bf(float f){
  unsigned u = __float_as_uint(f);
  return (unsigned short)((u + 0x7fffu + ((u >> 16) & 1u)) >> 16);  // RNE
}
__device__ __forceinline__ unsigned pk2(float a, float b){
  return ((unsigned)f2bf(b) << 16) | f2bf(a);
}
__device__ __forceinline__ float silu(float x){ return x / (1.0f + __expf(-x)); }

// ---- scan tail (R8 body): radius graph -> 16B edge records {diff,j}, publish units
__device__ __forceinline__ void scan_tail(
    int row, int rowsel, int t256, bool v, const float* __restrict__ x,
    uint4* __restrict__ erec, int* __restrict__ units, int* __restrict__ ucntSlot,
    int* scn){
  int* scnt  = scn + rowsel*2;
  int* sbase = scnt + 1;
  if (t256 == 0) *scnt = 0;
  __syncthreads();
  if (v) {
    float xi0 = x[row*3], xi1 = x[row*3+1], xi2 = x[row*3+2];
    for (int j = t256; j < 384; j += 256) {
      float d0 = xi0-x[j*3], d1 = xi1-x[j*3+1], d2 = xi2-x[j*3+2];
      float dd = d0*d0 + d1*d1 + d2*d2;
      bool msk = ((dd < CUTOFF2) && (j != row)) || (j == row-1) || (j == row+1);
      if (msk) {
        int ss = atomicAdd(scnt, 1);
        ER er; er.e.dx = d0; er.e.dy = d1; er.e.dz = d2; er.e.j = (unsigned)j;
        erec[row*384 + ss] = er.u4;
      }
    }
  }
  __syncthreads();
  if (v) {
    int cnt = *scnt;
    int p = (32 - (cnt & 31)) & 31;
    if (t256 < p) {
      ER er; er.e.dx = 0.f; er.e.dy = 0.f; er.e.dz = 0.f; er.e.j = (unsigned)row;
      erec[row*384 + cnt + t256] = er.u4;
    }
    if (t256 == 0) *sbase = atomicAdd(ucntSlot, (cnt + 31) >> 5);
  }
  __syncthreads();
  if (v) {
    int cnt = *scnt, nu = (cnt + 31) >> 5;
    if (t256 < nu) {
      int nv = cnt - (t256 << 5); if (nv > 32) nv = 32;
      units[*sbase + t256] = row | (t256 << 9) | (nv << 13);
    }
  }
}

// ---- K1: pack (0..155) | mean (156) | proj+seed+scan0 (157..348, 2 rows each, R8 body)
__global__ __launch_bounds__(512) void k_init(
    const float* __restrict__ eW1, const float* __restrict__ eW2,
    const float* __restrict__ cW1, unsigned* __restrict__ pk,
    const float* __restrict__ anchor, const float* __restrict__ z,
    const float* __restrict__ pW, const float* __restrict__ pb,
    const float* __restrict__ eb1, float* __restrict__ h,
    unsigned short* __restrict__ hbf, float* __restrict__ A,
    float* __restrict__ agg, float* __restrict__ xB, float* __restrict__ meanw,
    uint4* __restrict__ erec, int* __restrict__ units, int* __restrict__ ucnt0){
  const int b = blockIdx.x, tid = threadIdx.x;
  if (b < 156) {
    // weight pack into MFMA B-frag order (one element per thread; 156*512 = 3*PK_L)
    int t = b*512 + tid;
    int layer = t / PK_L, r = t % PK_L;
    const float* src; int fr; int isWe = 0;
    if (r < PK_WE)        { fr = r;          src = eW1 + (layer*272 + 128)*128; }
    else if (r < PK_W2)   { fr = r - PK_WE;  src = eW1 + (layer*272 + 256)*128; isWe = 1; }
    else if (r < PK_C1)   { fr = r - PK_W2;  src = eW2 + layer*128*128; }
    else                  { fr = r - PK_C1;  src = cW1 + layer*128*128; }
    int tp = fr & 3, l = (fr >> 2) & 63, nc = fr >> 8;
    int n, k;
    if (!isWe) { n = nc >> 2; int c = nc & 3; k = c*32 + ((l>>4)<<3) + 2*tp; }
    else       { n = nc;                      k = ((l>>4)<<3) + 2*tp; }
    int nn = n*16 + (l & 15);
    float w0, w1;
    if (isWe) { w0 = (k < 16)   ? src[k*128+nn]     : 0.f;
                w1 = (k+1 < 16) ? src[(k+1)*128+nn] : 0.f; }
    else      { w0 = src[k*128+nn]; w1 = src[(k+1)*128+nn]; }
    pk[t] = ((unsigned)f2bf(w1) << 16) | f2bf(w0);
    return;
  }
  if (b == 156) {
    __shared__ float ssum[3];
    if (tid < 3) ssum[tid] = 0.f;
    __syncthreads();
    if (tid < 384) {
      atomicAdd(&ssum[0], anchor[tid*3]);
      atomicAdd(&ssum[1], anchor[tid*3+1]);
      atomicAdd(&ssum[2], anchor[tid*3+2]);
    }
    __syncthreads();
    if (tid < 3) meanw[tid] = ssum[tid]*(1.f/384.f);
    return;
  }
  // proj + scan L0 (mean-free: scan on raw anchor; xB seeded uncentered)
  __shared__ float sb2[2*768];
  __shared__ int scn[4];
  const int rowsel = tid >> 8, half = (tid >> 7) & 1, o = tid & 127, t256 = tid & 255;
  const int row = (b - 157)*2 + rowsel;   // 192 blocks x 2 rows = 384
  float* sb = sb2 + rowsel*768;
  float* sh = sb; float* part = sb + 512; float* sz = sb + 640;

  if (half == 0) { if (o < 64) sz[o] = z[row*64 + o]; }
  else           agg[row*128 + o] = 0.f;
  if (half == 0 && o < 3) xB[row*3 + o] = anchor[row*3 + o];
  __syncthreads();
  float pp = 0.f;
  {
    int k0 = half*32;
    float p0=0,p1=0,p2=0,p3=0;
    #pragma unroll 8
    for (int k = k0; k < k0+32; k += 4) {
      p0 += sz[k]   * pW[k*128 + o];
      p1 += sz[k+1] * pW[(k+1)*128 + o];
      p2 += sz[k+2] * pW[(k+2)*128 + o];
      p3 += sz[k+3] * pW[(k+3)*128 + o];
    }
    pp = (p0+p1)+(p2+p3);
    if (half) part[o] = pp;
  }
  __syncthreads();
  if (!half) {
    float hh = pb[o] + pp + part[o];
    h[row*128 + o] = hh; sh[o] = hh;
    hbf[row*128 + o] = f2bf(hh);
  }
  __syncthreads();
  float cc = 0.f;
  {
    int k0 = half*64;
    float c0=0,c1=0,c2=0,c3=0;
    #pragma unroll 16
    for (int k = k0; k < k0+64; k += 4) {
      c0 += sh[k]   * eW1[k*128 + o];
      c1 += sh[k+1] * eW1[(k+1)*128 + o];
      c2 += sh[k+2] * eW1[(k+2)*128 + o];
      c3 += sh[k+3] * eW1[(k+3)*128 + o];
    }
    cc = (c0+c1)+(c2+c3);
    if (half) part[o] = cc;
  }
  __syncthreads();
  if (!half) A[row*128 + o] = eb1[o] + cc + part[o];

  scan_tail(row, rowsel, t256, true, anchor, erec, units, ucnt0, scn);
}

// ---- node (exact R8 body + meanp for final out-centering): 256 blocks x 512
__global__ __launch_bounds__(512) void k_node(
    const float* __restrict__ nW1, const float* __restrict__ nb1,
    const float* __restrict__ nW2, const float* __restrict__ nb2,
    const float* __restrict__ eW1n, const float* __restrict__ eb1n,
    float* __restrict__ h, unsigned short* __restrict__ hbf,
    float* __restrict__ agg, float* __restrict__ A,
    const float* __restrict__ xsrc, float* __restrict__ xdst,
    const float* __restrict__ meanp,
    uint4* __restrict__ erec, int* __restrict__ units, int* __restrict__ ucntSlot){
  __shared__ float sb2[2*768];
  __shared__ int scn[4];
  const int tid = threadIdx.x;
  const int rowsel = tid >> 8, half = (tid >> 7) & 1, o = tid & 127, t256 = tid & 255;
  const int row = blockIdx.x + 256*rowsel;
  const bool v = row < NN;
  float* sb = sb2 + rowsel*768;
  float* sh = sb; float* sg = sb+128; float* st = sb+256; float* shn = sb+384; float* part = sb+512;

  if (v) {
    if (half == 0) {
      sh[o] = h[row*128 + o];
      if (o < 3) {
        float m = meanp ? meanp[o] : 0.f;
        xdst[row*3 + o] = xsrc[row*3 + o] - m;
      }
    } else {
      sg[o] = agg[row*128 + o]; agg[row*128 + o] = 0.f;
    }
  }
  __syncthreads();
  float aa = 0.f;
  if (v) {
    const float* src = half ? sg : sh;
    const float* wb  = nW1 + half*128*128;
    float a0=0,a1=0,a2=0,a3=0;
    #pragma unroll 16
    for (int k = 0; k < 128; k += 4) {
      a0 += src[k]   * wb[k*128 + o];
      a1 += src[k+1] * wb[(k+1)*128 + o];
      a2 += src[k+2] * wb[(k+2)*128 + o];
      a3 += src[k+3] * wb[(k+3)*128 + o];
    }
    aa = (a0+a1)+(a2+a3);
    if (half) part[o] = aa;
  }
  __syncthreads();
  if (v && !half) st[o] = silu(nb1[o] + aa + part[o]);
  __syncthreads();
  float bb = 0.f;
  if (v) {
    int k0 = half*64;
    float b0=0,b1=0,b2=0,b3=0;
    #pragma unroll 16
    for (int k = k0; k < k0+64; k += 4) {
      b0 += st[k]   * nW2[k*128 + o];
      b1 += st[k+1] * nW2[(k+1)*128 + o];
      b2 += st[k+2] * nW2[(k+2)*128 + o];
      b3 += st[k+3] * nW2[(k+3)*128 + o];
    }
    bb = (b0+b1)+(b2+b3);
    if (half) part[o] = bb;
  }
  __syncthreads();
  if (v && !half) {
    float hn = sh[o] + nb2[o] + bb + part[o];
    h[row*128 + o] = hn; shn[o] = hn;
    hbf[row*128 + o] = f2bf(hn);
  }
  __syncthreads();
  float cc = 0.f;
  if (v) {
    int k0 = half*64;
    float c0=0,c1=0,c2=0,c3=0;
    #pragma unroll 16
    for (int k = k0; k < k0+64; k += 4) {
      c0 += shn[k]   * eW1n[k*128 + o];
      c1 += shn[k+1] * eW1n[(k+1)*128 + o];
      c2 += shn[k+2] * eW1n[(k+2)*128 + o];
      c3 += shn[k+3] * eW1n[(k+3)*128 + o];
    }
    cc = (c0+c1)+(c2+c3);
    if (half) part[o] = cc;
  }
  __syncthreads();
  if (v && !half) A[row*128 + o] = eb1n[o] + cc + part[o];

  scan_tail(row, rowsel, t256, v, xsrc, erec, units, ucntSlot, scn);
}

// ---- C-layout -> A-frag transpose via per-wave f32 LDS pad (wave-private, no fences)
#define TRANSFORM(VA, VB, FA, FB)                                              \
  _Pragma("unroll")                                                            \
  for (int c = 0; c < 4; ++c) {                                                \
    _Pragma("unroll")                                                          \
    for (int tl = 0; tl < 2; ++tl) {                                           \
      int t = 2*c + tl;                                                        \
      _Pragma("unroll")                                                        \
      for (int r = 0; r < 4; ++r) {                                            \
        stg[(quad*4 + r)*36 + tl*16 + col0] = VA[t][r];                        \
        stg[(16 + quad*4 + r)*36 + tl*16 + col0] = VB[t][r];                   \
      }                                                                        \
    }                                                                          \
    float4 lo = *(const float4*)(stg + col0*36 + quad*8);                      \
    float4 hi = *(const float4*)(stg + col0*36 + quad*8 + 4);                  \
    FA[c].u = make_uint4(pk2(lo.x,lo.y), pk2(lo.z,lo.w),                       \
                         pk2(hi.x,hi.y), pk2(hi.z,hi.w));                      \
    float4 lo2 = *(const float4*)(stg + (16 + col0)*36 + quad*8);              \
    float4 hi2 = *(const float4*)(stg + (16 + col0)*36 + quad*8 + 4);          \
    FB[c].u = make_uint4(pk2(lo2.x,lo2.y), pk2(lo2.z,lo2.w),                   \
                         pk2(hi2.x,hi2.y), pk2(hi2.z,hi2.w));                  \
  }

// ---- MFMA edge kernel (exact R8 body): wave = one unit, block-first spread
__global__ __launch_bounds__(512, 1) void k_edge(
    float* __restrict__ x_out, const float* __restrict__ Ag,
    const unsigned short* __restrict__ hbf, const uint4* __restrict__ erec,
    const int* __restrict__ units, const int* __restrict__ Ucnt,
    float* __restrict__ agg, const unsigned* __restrict__ pkl,
    const float* __restrict__ eb2g, const float* __restrict__ cb1g,
    const float* __restrict__ cw2g){
  extern __shared__ unsigned smem[];
  const int tid = threadIdx.x, q = tid & 63, s = tid >> 6;
  const int U = Ucnt[0];
  if (blockIdx.x >= U) return;

  for (int idx = tid; idx < PK_L/4; idx += 512)
    ((uint4*)smem)[idx] = ((const uint4*)pkl)[idx];
  __syncthreads();

  const int col0 = q & 15, quad = q >> 4;
  float eb2v[8], cb1v[8], cw2v[8];
  #pragma unroll
  for (int t = 0; t < 8; ++t) {
    int c = t*16 + col0;
    eb2v[t] = eb2g[c]; cb1v[t] = cb1g[c]; cw2v[t] = cw2g[c];
  }
  float* stg = (float*)(smem + PK_L) + s*STG_F32;
  const f32x4 z4 = {0.f, 0.f, 0.f, 0.f};
  union U8 { uint4 u; bf16x8 v; };

  for (int u = blockIdx.x + 256*s; u < U; u += 2048) {
    const int desc = units[u];
    const int i = desc & 511, b = (desc >> 9) & 15, nvalid = (desc >> 13) & 63;
    float Aval[8];
    #pragma unroll
    for (int t = 0; t < 8; ++t) Aval[t] = Ag[i*128 + t*16 + col0];
    ER e0, e1;
    e0.u4 = erec[i*384 + b*32 + col0];
    e1.u4 = erec[i*384 + b*32 + 16 + col0];
    const int j0 = (int)e0.e.j, j1 = (int)e1.e.j;
    const float d0x = e0.e.dx, d0y = e0.e.dy, d0z = e0.e.dz;
    const float d1x = e1.e.dx, d1y = e1.e.dy, d1z = e1.e.dz;
    const float dd0 = sqrtf(d0x*d0x + d0y*d0y + d0z*d0z);
    const float dd1 = sqrtf(d1x*d1x + d1y*d1y + d1z*d1z);

    U8 ha0[4], ha1[4];
    #pragma unroll
    for (int c = 0; c < 4; ++c) {
      ha0[c].u = *(const uint4*)(hbf + j0*128 + c*32 + quad*8);
      ha1[c].u = *(const uint4*)(hbf + j1*128 + c*32 + quad*8);
    }

    U8 cve0, cve1;
    if (q < 32) {
      #pragma unroll
      for (int tp = 0; tp < 4; ++tp) {
        float k0 = (float)(quad*8 + 2*tp);
        float t00 = dd0 - 0.8f*k0, t01 = dd0 - 0.8f*(k0+1.f);
        float t10 = dd1 - 0.8f*k0, t11 = dd1 - 0.8f*(k0+1.f);
        (&cve0.u.x)[tp] = pk2(__expf(-GAMMA*t00*t00), __expf(-GAMMA*t01*t01));
        (&cve1.u.x)[tp] = pk2(__expf(-GAMMA*t10*t10), __expf(-GAMMA*t11*t11));
      }
    } else { cve0.u = make_uint4(0,0,0,0); cve1.u = make_uint4(0,0,0,0); }

    // GEMM1: m1 = silu(h_j@W1b + e@We + A_i), 32 rows
    f32x4 acc0[8], acc1[8];
    #pragma unroll
    for (int t = 0; t < 8; ++t) { acc0[t] = z4; acc1[t] = z4; }
    #pragma unroll
    for (int t = 0; t < 8; ++t) {
      #pragma unroll
      for (int c = 0; c < 4; ++c) {
        bf16x8 w = *(const bf16x8*)(smem + ((t*4 + c)*64 + q)*4);
        acc0[t] = __builtin_amdgcn_mfma_f32_16x16x32_bf16(ha0[c].v, w, acc0[t], 0, 0, 0);
        acc1[t] = __builtin_amdgcn_mfma_f32_16x16x32_bf16(ha1[c].v, w, acc1[t], 0, 0, 0);
      }
      bf16x8 we = *(const bf16x8*)(smem + PK_WE + (t*64 + q)*4);
      acc0[t] = __builtin_amdgcn_mfma_f32_16x16x32_bf16(cve0.v, we, acc0[t], 0, 0, 0);
      acc1[t] = __builtin_amdgcn_mfma_f32_16x16x32_bf16(cve1.v, we, acc1[t], 0, 0, 0);
    }
    #pragma unroll
    for (int t = 0; t < 8; ++t)
      #pragma unroll
      for (int r = 0; r < 4; ++r) {
        acc0[t][r] = silu(acc0[t][r] + Aval[t]);
        acc1[t][r] = silu(acc1[t][r] + Aval[t]);
      }

    U8 a20[4], a21[4];
    TRANSFORM(acc0, acc1, a20, a21);

    // GEMM2: m = silu(m1@eW2 + eb2)
    f32x4 m0[8], m1v[8];
    #pragma unroll
    for (int t = 0; t < 8; ++t) { m0[t] = z4; m1v[t] = z4; }
    #pragma unroll
    for (int t = 0; t < 8; ++t)
      #pragma unroll
      for (int c = 0; c < 4; ++c) {
        bf16x8 w = *(const bf16x8*)(smem + PK_W2 + ((t*4 + c)*64 + q)*4);
        m0[t] = __builtin_amdgcn_mfma_f32_16x16x32_bf16(a20[c].v, w, m0[t], 0, 0, 0);
        m1v[t] = __builtin_amdgcn_mfma_f32_16x16x32_bf16(a21[c].v, w, m1v[t], 0, 0, 0);
      }
    #pragma unroll
    for (int t = 0; t < 8; ++t) {
      float cs = 0.f;
      #pragma unroll
      for (int r = 0; r < 4; ++r) {
        m0[t][r] = silu(m0[t][r] + eb2v[t]);
        m1v[t][r] = silu(m1v[t][r] + eb2v[t]);
        if (quad*4 + r < nvalid) cs += m0[t][r];
        if (16 + quad*4 + r < nvalid) cs += m1v[t][r];
      }
      cs += __shfl_xor(cs, 16); cs += __shfl_xor(cs, 32);
      if (q < 16) atomicAdd(&agg[i*128 + t*16 + q], cs);
    }

    U8 a30[4], a31[4];
    TRANSFORM(m0, m1v, a30, a31);

    // GEMM3: c1 = silu(m@cW1 + cb1); w_row = c1 . cW2
    f32x4 c30[8], c31[8];
    #pragma unroll
    for (int t = 0; t < 8; ++t) { c30[t] = z4; c31[t] = z4; }
    #pragma unroll
    for (int t = 0; t < 8; ++t)
      #pragma unroll
      for (int c = 0; c < 4; ++c) {
        bf16x8 w = *(const bf16x8*)(smem + PK_C1 + ((t*4 + c)*64 + q)*4);
        c30[t] = __builtin_amdgcn_mfma_f32_16x16x32_bf16(a30[c].v, w, c30[t], 0, 0, 0);
        c31[t] = __builtin_amdgcn_mfma_f32_16x16x32_bf16(a31[c].v, w, c31[t], 0, 0, 0);
      }
    float p0[4], p1[4];
    #pragma unroll
    for (int r = 0; r < 4; ++r) {
      float pa = 0.f, pb = 0.f;
      #pragma unroll
      for (int t = 0; t < 8; ++t) {
        pa += silu(c30[t][r] + cb1v[t]) * cw2v[t];
        pb += silu(c31[t][r] + cb1v[t]) * cw2v[t];
      }
      if (quad*4 + r >= nvalid) pa = 0.f;
      if (16 + quad*4 + r >= nvalid) pb = 0.f;
      p0[r] = pa; p1[r] = pb;
    }
    #pragma unroll
    for (int r = 0; r < 4; ++r)
      #pragma unroll
      for (int off = 1; off < 16; off <<= 1) {
        p0[r] += __shfl_xor(p0[r], off);
        p1[r] += __shfl_xor(p1[r], off);
      }
    float dx0 = 0.f, dx1 = 0.f, dx2 = 0.f;
    #pragma unroll
    for (int r = 0; r < 4; ++r) {
      int el = quad*4 + r;
      float s0 = __shfl(d0x, el), s1 = __shfl(d0y, el), s2 = __shfl(d0z, el);
      if (col0 == 0) { dx0 += p0[r]*s0; dx1 += p0[r]*s1; dx2 += p0[r]*s2; }
      float u0 = __shfl(d1x, el), u1 = __shfl(d1y, el), u2 = __shfl(d1z, el);
      if (col0 == 0) { dx0 += p1[r]*u0; dx1 += p1[r]*u1; dx2 += p1[r]*u2; }
    }
    dx0 += __shfl_xor(dx0, 16); dx0 += __shfl_xor(dx0, 32);
    dx1 += __shfl_xor(dx1, 16); dx1 += __shfl_xor(dx1, 32);
    dx2 += __shfl_xor(dx2, 16); dx2 += __shfl_xor(dx2, 32);
    if (q == 0) {
      atomicAdd(&x_out[i*3 + 0], dx0);
      atomicAdd(&x_out[i*3 + 1], dx1);
      atomicAdd(&x_out[i*3 + 2], dx2);
    }
  }
}

extern "C" void kernel_launch(void* const* d_in, const int* in_sizes, int n_in,
                              void* d_out, int out_size, void* d_ws, size_t ws_size,
                              hipStream_t stream){
  const float* z      = (const float*)d_in[0];
  const float* anchor = (const float*)d_in[1];
  const float* projW  = (const float*)d_in[2];
  const float* projb  = (const float*)d_in[3];
  const float* eW1    = (const float*)d_in[4];
  const float* eb1    = (const float*)d_in[5];
  const float* eW2    = (const float*)d_in[6];
  const float* eb2    = (const float*)d_in[7];
  const float* nW1    = (const float*)d_in[8];
  const float* nb1    = (const float*)d_in[9];
  const float* nW2    = (const float*)d_in[10];
  const float* nb2    = (const float*)d_in[11];
  const float* cW1    = (const float*)d_in[12];
  const float* cb1    = (const float*)d_in[13];
  const float* cW2    = (const float*)d_in[14];
  float* out = (float*)d_out;

  char* w = (char*)d_ws;
  float* xA  = (float*)(w + O_XA);
  float* xB  = (float*)(w + O_XB);
  float* h   = (float*)(w + O_H);
  float* A   = (float*)(w + O_A);
  float* agg = (float*)(w + O_AGG);
  unsigned short* hbf = (unsigned short*)(w + O_HBF);
  uint4* erec = (uint4*)(w + O_EREC);
  int* units = (int*)(w + O_UNITS);
  int* ucnt  = (int*)(w + O_UCNT);
  float* meanw = (float*)(w + O_MEAN);
  unsigned* pk = (unsigned*)(w + O_PK);

  hipFuncSetAttribute((const void*)k_edge, hipFuncAttributeMaxDynamicSharedMemorySize, EDGE_SMEM);

  hipMemsetAsync(ucnt, 0, 12, stream);
  k_init<<<349, 512, 0, stream>>>(eW1, eW2, cW1, pk, anchor, z, projW, projb,
                                  eb1, h, hbf, A, agg, xB, meanw, erec, units, ucnt + 0);
  // layer 0: edges from anchor geometry, accumulate into xB (seeded = anchor)
  k_edge<<<256, 512, EDGE_SMEM, stream>>>(xB, A, hbf, erec, units, ucnt + 0,
                                          agg, pk, eb2, cb1, cW2);
  k_node<<<256, 512, 0, stream>>>(nW1, nb1, nW2, nb2, eW1 + 272*128, eb1 + 128,
                                  h, hbf, agg, A, xB, xA, (const float*)nullptr,
                                  erec, units, ucnt + 1);
  // layer 1: edges from xB geometry, accumulate into xA (seeded = xB)
  k_edge<<<256, 512, EDGE_SMEM, stream>>>(xA, A, hbf, erec, units, ucnt + 1,
                                          agg, pk + PK_L, eb2 + 128, cb1 + 128, cW2 + 128);
  k_node<<<256, 512, 0, stream>>>(nW1 + 256*128, nb1 + 128, nW2 + 128*128, nb2 + 128,
                                  eW1 + 2*272*128, eb1 + 256,
                                  h, hbf, agg, A, xA, out, meanw,
                                  erec, units, ucnt + 2);
  // layer 2: edges from xA geometry, accumulate into out (seeded = xA - mean)
  k_edge<<<256, 512, EDGE_SMEM, stream>>>(out, A, hbf, erec, units, ucnt + 2,
                                          agg, pk + 2*PK_L, eb2 + 256, cb1 + 256, cW2 + 256);
}